// Round 4
// baseline (498.994 us; speedup 1.0000x reference)
//
#include <hip/hip_runtime.h>
#include <math.h>

#define NN 100000
#define FEAT 128
#define NHEAD 4
#define BSH 9                      // 512 nodes per bucket
#define BNODES 512
#define NBUCK 196                  // ceil(NN / 512)
#define BCAP 16384                 // colidx LDS image capacity (avg span ~8700)
#define PA_EPT 16                  // phase-A edges per thread
#define GTILES 6250                // 100000 / 16
#define GEMMB 1563                 // gemm grid blocks: 4 tiles per block (1 per wave)
#define HSTRIDE 136                // h-tile row stride in ushorts (bank-conflict pad)
#define SRCMASK 0x1FFFF            // low 17 bits: src id (NN < 2^17)

typedef unsigned int uint;
typedef unsigned short ushort;
typedef __attribute__((ext_vector_type(8))) short short8;
typedef __attribute__((ext_vector_type(4))) float fx4;

__device__ __forceinline__ float lrelu(float v) { return v > 0.f ? v : 0.2f * v; }

__device__ __forceinline__ ushort f2bf(float f) {          // RNE bf16
    uint u = __float_as_uint(f);
    return (ushort)((u + 0x7fffu + ((u >> 16) & 1u)) >> 16);
}
__device__ __forceinline__ float bf_lo(uint u) { return __uint_as_float(u << 16); }
__device__ __forceinline__ float bf_hi(uint u) { return __uint_as_float(u & 0xffff0000u); }

__device__ __forceinline__ short8 pack8f(const float* p) {
    float4 a = *(const float4*)p, b = *(const float4*)(p + 4);
    short8 v;
    v[0] = (short)f2bf(a.x); v[1] = (short)f2bf(a.y);
    v[2] = (short)f2bf(a.z); v[3] = (short)f2bf(a.w);
    v[4] = (short)f2bf(b.x); v[5] = (short)f2bf(b.y);
    v[6] = (short)f2bf(b.z); v[7] = (short)f2bf(b.w);
    return v;
}

// ======================= shared aggr core =======================
// 16 lanes per node; lane covers dims lane*8..lane*8+7. Returns post-ELU o[8].
#define AGGR_STEP(hv, wgt)                                                    \
    a0 = fmaf(wgt, bf_lo(hv.x), a0); a1 = fmaf(wgt, bf_hi(hv.x), a1);        \
    a2 = fmaf(wgt, bf_lo(hv.y), a2); a3 = fmaf(wgt, bf_hi(hv.y), a3);        \
    a4 = fmaf(wgt, bf_lo(hv.z), a4); a5 = fmaf(wgt, bf_hi(hv.z), a5);        \
    a6 = fmaf(wgt, bf_lo(hv.w), a6); a7 = fmaf(wgt, bf_hi(hv.w), a7);

#define PROC4(cv)                                                             \
    {                                                                         \
        int s0 = cv.x, s1 = cv.y, s2 = cv.z, s3 = cv.w;                       \
        float w0 = __expf(lrelu(al_s[s0*4 + head] + ald_h));                  \
        float w1 = __expf(lrelu(al_s[s1*4 + head] + ald_h));                  \
        float w2 = __expf(lrelu(al_s[s2*4 + head] + ald_h));                  \
        float w3 = __expf(lrelu(al_s[s3*4 + head] + ald_h));                  \
        uint4 h0 = ((const uint4*)(hbf + (size_t)s0 * FEAT))[lane];           \
        uint4 h1 = ((const uint4*)(hbf + (size_t)s1 * FEAT))[lane];           \
        uint4 h2 = ((const uint4*)(hbf + (size_t)s2 * FEAT))[lane];           \
        uint4 h3 = ((const uint4*)(hbf + (size_t)s3 * FEAT))[lane];           \
        ssum += (w0 + w1) + (w2 + w3);                                        \
        AGGR_STEP(h0, w0) AGGR_STEP(h1, w1) AGGR_STEP(h2, w2) AGGR_STEP(h3, w3) \
    }

#define PROC8(cva, cvb)                                                       \
    {                                                                         \
        int s0 = cva.x, s1 = cva.y, s2 = cva.z, s3 = cva.w;                   \
        int s4 = cvb.x, s5 = cvb.y, s6 = cvb.z, s7 = cvb.w;                   \
        uint4 h0 = ((const uint4*)(hbf + (size_t)s0 * FEAT))[lane];           \
        uint4 h1 = ((const uint4*)(hbf + (size_t)s1 * FEAT))[lane];           \
        uint4 h2 = ((const uint4*)(hbf + (size_t)s2 * FEAT))[lane];           \
        uint4 h3 = ((const uint4*)(hbf + (size_t)s3 * FEAT))[lane];           \
        uint4 h4 = ((const uint4*)(hbf + (size_t)s4 * FEAT))[lane];           \
        uint4 h5 = ((const uint4*)(hbf + (size_t)s5 * FEAT))[lane];           \
        uint4 h6 = ((const uint4*)(hbf + (size_t)s6 * FEAT))[lane];           \
        uint4 h7 = ((const uint4*)(hbf + (size_t)s7 * FEAT))[lane];           \
        float w0 = __expf(lrelu(al_s[s0*4 + head] + ald_h));                  \
        float w1 = __expf(lrelu(al_s[s1*4 + head] + ald_h));                  \
        float w2 = __expf(lrelu(al_s[s2*4 + head] + ald_h));                  \
        float w3 = __expf(lrelu(al_s[s3*4 + head] + ald_h));                  \
        float w4 = __expf(lrelu(al_s[s4*4 + head] + ald_h));                  \
        float w5 = __expf(lrelu(al_s[s5*4 + head] + ald_h));                  \
        float w6 = __expf(lrelu(al_s[s6*4 + head] + ald_h));                  \
        float w7 = __expf(lrelu(al_s[s7*4 + head] + ald_h));                  \
        ssum += ((w0 + w1) + (w2 + w3)) + ((w4 + w5) + (w6 + w7));            \
        AGGR_STEP(h0, w0) AGGR_STEP(h1, w1) AGGR_STEP(h2, w2) AGGR_STEP(h3, w3) \
        AGGR_STEP(h4, w4) AGGR_STEP(h5, w5) AGGR_STEP(h6, w6) AGGR_STEP(h7, w7) \
    }

__device__ __forceinline__ void aggr_node(
    const int* __restrict__ row_ptr, const int* __restrict__ colidx,
    const ushort* __restrict__ hbf, const float* __restrict__ al_s,
    const float* __restrict__ al_d, const float* __restrict__ bias,
    int node, int lane, float* __restrict__ o)
{
    const int head = lane >> 2;
    float ald_h = al_d[node * 4 + head];
    int beg = row_ptr[node], end = row_ptr[node + 1];

    float ssum = 0.f;
    float a0=0.f,a1=0.f,a2=0.f,a3=0.f,a4=0.f,a5=0.f,a6=0.f,a7=0.f;

    int p = beg;
    int4 ca, cb;
    if (p + 8 <= end) {
        ca = *(const int4*)&colidx[p];
        cb = *(const int4*)&colidx[p + 4];
    }
    while (p + 16 <= end) {
        int4 na = *(const int4*)&colidx[p + 8];    // prefetch next 8-batch
        int4 nb = *(const int4*)&colidx[p + 12];
        PROC8(ca, cb)
        ca = na; cb = nb;
        p += 8;
    }
    if (p + 8 <= end) { PROC8(ca, cb) p += 8; }
    if (p + 4 <= end) {
        int4 c4 = *(const int4*)&colidx[p];
        PROC4(c4)
        p += 4;
    }
    for (; p < end; ++p) {
        int sn = colidx[p];
        float wq = __expf(lrelu(al_s[sn*4 + head] + ald_h));
        uint4 hv = ((const uint4*)(hbf + (size_t)sn * FEAT))[lane];
        ssum += wq;
        AGGR_STEP(hv, wq)
    }

    float inv = 1.f / (ssum + 1e-16f);
    const float* bp = bias + lane * 8;
    float oo[8] = {a0,a1,a2,a3,a4,a5,a6,a7};
    #pragma unroll
    for (int k = 0; k < 8; ++k) {
        float v = oo[k] * inv + bp[k];
        o[k] = v > 0.f ? v : __expf(v) - 1.f;
    }
}

// ======================= MFMA GEMM body (layer 0 standalone) =======================
template <bool FP32IN>
__device__ __forceinline__ void gemm_body(
    const void* __restrict__ in, const float* __restrict__ W,
    const float* __restrict__ a_src, const float* __restrict__ a_dst,
    ushort* __restrict__ hbf, float* __restrict__ al_s, float* __restrict__ al_d,
    int bid)
{
    __shared__ __align__(16) ushort WA[FEAT * FEAT];       // 32 KiB, fragment-ordered
    const int t = threadIdx.x;
    const int lane = t & 63;
    const int node_l = lane & 15, q = lane >> 4;
    const int tile = bid * 4 + (t >> 6);
    const bool valid = tile < GTILES;
    const int n0 = tile * 16;

    // issue b-row loads FIRST: HBM latency hides under the 64-iter W staging
    short8 b0, b1, b2, b3;
    const ushort* inbf = (const ushort*)in;
    const float*  inf  = (const float*)in;
    if (valid) {
        if (FP32IN) {
            const float* rf = inf + (size_t)(n0 + node_l) * FEAT + q * 8;
            b0 = pack8f(rf);
            b1 = pack8f(rf + 32);
            b2 = pack8f(rf + 64);
            b3 = pack8f(rf + 96);
        } else {
            const ushort* rowp = inbf + (size_t)(n0 + node_l) * FEAT + q * 8;
            b0 = *(const short8*)(rowp);
            b1 = *(const short8*)(rowp + 32);
            b2 = *(const short8*)(rowp + 64);
            b3 = *(const short8*)(rowp + 96);
        }
    }

    for (int idx = t; idx < FEAT * FEAT; idx += 256) {
        int k = idx >> 7, m = idx & 127;
        int mt = m >> 4, kt = k >> 5, qq = (k >> 3) & 3, j = k & 7;
        int ln = qq * 16 + (m & 15);
        WA[((mt * 4 + kt) * 64 + ln) * 8 + j] = f2bf(W[idx]);
    }
    __syncthreads();
    if (!valid) return;

    fx4 zero = {0.f, 0.f, 0.f, 0.f};
    fx4 acc[8];
    #pragma unroll
    for (int mt = 0; mt < 8; ++mt) acc[mt] = zero;
    #pragma unroll
    for (int kt = 0; kt < 4; ++kt) {
        short8 b = (kt == 0) ? b0 : (kt == 1) ? b1 : (kt == 2) ? b2 : b3;
        #pragma unroll
        for (int mt = 0; mt < 8; ++mt) {
            short8 a = *(const short8*)&WA[((mt * 4 + kt) * 64 + lane) * 8];
            acc[mt] = __builtin_amdgcn_mfma_f32_16x16x32_bf16(a, b, acc[mt], 0, 0, 0);
        }
    }

    float ps[4] = {0.f, 0.f, 0.f, 0.f};
    float pd[4] = {0.f, 0.f, 0.f, 0.f};
    #pragma unroll
    for (int mt = 0; mt < 8; ++mt) {
        float4 as4 = *(const float4*)(a_src + mt * 16 + q * 4);
        float4 ad4 = *(const float4*)(a_dst + mt * 16 + q * 4);
        ps[mt >> 1] += acc[mt][0] * as4.x + acc[mt][1] * as4.y + acc[mt][2] * as4.z + acc[mt][3] * as4.w;
        pd[mt >> 1] += acc[mt][0] * ad4.x + acc[mt][1] * ad4.y + acc[mt][2] * ad4.z + acc[mt][3] * ad4.w;
        ushort4 hv;
        hv.x = f2bf(acc[mt][0]); hv.y = f2bf(acc[mt][1]);
        hv.z = f2bf(acc[mt][2]); hv.w = f2bf(acc[mt][3]);
        *(ushort4*)(hbf + (size_t)(n0 + node_l) * FEAT + mt * 16 + q * 4) = hv;
    }
    #pragma unroll
    for (int h = 0; h < 4; ++h) {
        ps[h] += __shfl_xor(ps[h], 16); ps[h] += __shfl_xor(ps[h], 32);
        pd[h] += __shfl_xor(pd[h], 16); pd[h] += __shfl_xor(pd[h], 32);
    }
    float vs = (q == 0) ? ps[0] : (q == 1) ? ps[1] : (q == 2) ? ps[2] : ps[3];
    float vd = (q == 0) ? pd[0] : (q == 1) ? pd[1] : (q == 2) ? pd[2] : pd[3];
    al_s[(n0 + node_l) * 4 + q] = vs;
    al_d[(n0 + node_l) * 4 + q] = vd;
}

// ---- phase-A body: bucket-binned (dst,src) pair scatter ----
__device__ __forceinline__ void phaseA_body(
    const int* __restrict__ ei, int E, int* bcursor, uint* __restrict__ pairs, int bid)
{
    __shared__ int lh[NBUCK], lb[NBUCK];
    int t = threadIdx.x;
    if (t < NBUCK) lh[t] = 0;
    __syncthreads();
    int base = bid * (256 * PA_EPT) + t;
    int s[PA_EPT], d[PA_EPT];
    #pragma unroll
    for (int k = 0; k < PA_EPT; ++k) {
        int i = base + k * 256;
        if (i < E)            { s[k] = ei[i]; d[k] = ei[E + i]; }
        else if (i < E + NN)  { s[k] = i - E; d[k] = s[k]; }
        else                  { s[k] = 0; d[k] = -1; }
        if (d[k] >= 0) atomicAdd(&lh[d[k] >> BSH], 1);
    }
    __syncthreads();
    if (t < NBUCK) {
        int c = lh[t];
        lb[t] = c ? atomicAdd(&bcursor[t], c) : 0;
        lh[t] = 0;
    }
    __syncthreads();
    #pragma unroll
    for (int k = 0; k < PA_EPT; ++k) {
        if (d[k] >= 0) {
            int b = d[k] >> BSH;
            int off = atomicAdd(&lh[b], 1);
            pairs[lb[b] + off] = ((uint)(d[k] & (BNODES - 1)) << 17) | (uint)s[k];
        }
    }
}

// ---- fused: gemm layer 0 (fp32 in) || CSR phase A (data-independent) ----
__global__ __launch_bounds__(256, 2) void gemm0_phaseA_kernel(
    const float* __restrict__ x, const float* __restrict__ W,
    const float* __restrict__ a_src, const float* __restrict__ a_dst,
    ushort* __restrict__ hbf, float* __restrict__ al_s, float* __restrict__ al_d,
    const int* __restrict__ ei, int E, int* bcursor, uint* __restrict__ pairs)
{
    if (blockIdx.x < GEMMB)
        gemm_body<true>(x, W, a_src, a_dst, hbf, al_s, al_d, blockIdx.x);
    else
        phaseA_body(ei, E, bcursor, pairs, blockIdx.x - GEMMB);
}

// ======================= fused aggr(L) + gemm(L+1) =======================
// r15: each wave aggregates its 16-node tile (fabric-bound gather), stores the
// 16x128 bf16 result in LDS (HS, HSTRIDE pad), then immediately runs the MFMA
// gemm on it. Removes ybf round-trip + standalone gemm1/gemm2 kernels; gemm
// compute hides under other blocks' gathers. hbf/als/ald ping-pong A<->B.
__global__ __launch_bounds__(256, 2) void aggr_gemm_fused_kernel(
    const int* __restrict__ row_ptr, const int* __restrict__ colidx,
    const ushort* __restrict__ hbf_in, const float* __restrict__ al_s_in,
    const float* __restrict__ al_d_in, const float* __restrict__ bias,
    const float* __restrict__ W, const float* __restrict__ a_src,
    const float* __restrict__ a_dst,
    ushort* __restrict__ hbf_out, float* __restrict__ al_s_out,
    float* __restrict__ al_d_out)
{
    __shared__ __align__(16) ushort WA[FEAT * FEAT];       // 32 KiB
    __shared__ __align__(16) ushort HS[4][16 * HSTRIDE];   // 17 KiB
    const int t = threadIdx.x;
    for (int idx = t; idx < FEAT * FEAT; idx += 256) {
        int k = idx >> 7, m = idx & 127;
        int mt = m >> 4, kt = k >> 5, qq = (k >> 3) & 3, j = k & 7;
        int ln = qq * 16 + (m & 15);
        WA[((mt * 4 + kt) * 64 + ln) * 8 + j] = f2bf(W[idx]);
    }
    __syncthreads();                     // only barrier; all later deps are wave-local

    const int wv = t >> 6, lane = t & 63;
    const int tile = blockIdx.x * 4 + wv;
    if (tile >= GTILES) return;
    const int n0 = tile * 16;
    const int ng = lane >> 4, l16 = lane & 15;

    // ---- aggr phase: 16 nodes, 4 per iteration (16 lanes each) ----
    #pragma unroll 1
    for (int it = 0; it < 4; ++it) {
        int node = n0 + it * 4 + ng;
        float o[8];
        aggr_node(row_ptr, colidx, hbf_in, al_s_in, al_d_in, bias, node, l16, o);
        uint4 u;
        u.x = (uint)f2bf(o[0]) | ((uint)f2bf(o[1]) << 16);
        u.y = (uint)f2bf(o[2]) | ((uint)f2bf(o[3]) << 16);
        u.z = (uint)f2bf(o[4]) | ((uint)f2bf(o[5]) << 16);
        u.w = (uint)f2bf(o[6]) | ((uint)f2bf(o[7]) << 16);
        *(uint4*)&HS[wv][(it * 4 + ng) * HSTRIDE + l16 * 8] = u;
    }

    // ---- gemm phase (r14 structure, B from LDS) ----
    const int node_l = l16, q = ng;
    short8 b0 = *(const short8*)&HS[wv][node_l * HSTRIDE +      q * 8];
    short8 b1 = *(const short8*)&HS[wv][node_l * HSTRIDE + 32 + q * 8];
    short8 b2 = *(const short8*)&HS[wv][node_l * HSTRIDE + 64 + q * 8];
    short8 b3 = *(const short8*)&HS[wv][node_l * HSTRIDE + 96 + q * 8];

    fx4 zero = {0.f, 0.f, 0.f, 0.f};
    fx4 acc[8];
    #pragma unroll
    for (int mt = 0; mt < 8; ++mt) acc[mt] = zero;
    #pragma unroll
    for (int kt = 0; kt < 4; ++kt) {
        short8 b = (kt == 0) ? b0 : (kt == 1) ? b1 : (kt == 2) ? b2 : b3;
        #pragma unroll
        for (int mt = 0; mt < 8; ++mt) {
            short8 a = *(const short8*)&WA[((mt * 4 + kt) * 64 + lane) * 8];
            acc[mt] = __builtin_amdgcn_mfma_f32_16x16x32_bf16(a, b, acc[mt], 0, 0, 0);
        }
    }

    float ps[4] = {0.f, 0.f, 0.f, 0.f};
    float pd[4] = {0.f, 0.f, 0.f, 0.f};
    #pragma unroll
    for (int mt = 0; mt < 8; ++mt) {
        float4 as4 = *(const float4*)(a_src + mt * 16 + q * 4);
        float4 ad4 = *(const float4*)(a_dst + mt * 16 + q * 4);
        ps[mt >> 1] += acc[mt][0] * as4.x + acc[mt][1] * as4.y + acc[mt][2] * as4.z + acc[mt][3] * as4.w;
        pd[mt >> 1] += acc[mt][0] * ad4.x + acc[mt][1] * ad4.y + acc[mt][2] * ad4.z + acc[mt][3] * ad4.w;
        ushort4 hv;
        hv.x = f2bf(acc[mt][0]); hv.y = f2bf(acc[mt][1]);
        hv.z = f2bf(acc[mt][2]); hv.w = f2bf(acc[mt][3]);
        *(ushort4*)(hbf_out + (size_t)(n0 + node_l) * FEAT + mt * 16 + q * 4) = hv;
    }
    #pragma unroll
    for (int h = 0; h < 4; ++h) {
        ps[h] += __shfl_xor(ps[h], 16); ps[h] += __shfl_xor(ps[h], 32);
        pd[h] += __shfl_xor(pd[h], 16); pd[h] += __shfl_xor(pd[h], 32);
    }
    float vs = (q == 0) ? ps[0] : (q == 1) ? ps[1] : (q == 2) ? ps[2] : ps[3];
    float vd = (q == 0) ? pd[0] : (q == 1) ? pd[1] : (q == 2) ? pd[2] : pd[3];
    al_s_out[(n0 + node_l) * 4 + q] = vs;
    al_d_out[(n0 + node_l) * 4 + q] = vd;
}

// ======================= CSR build (rest) =======================

__global__ __launch_bounds__(256) void bucket_hist_kernel(
    const int* __restrict__ ei, int E, int* bsize)
{
    __shared__ int lh[NBUCK];
    int t = threadIdx.x;
    if (t < NBUCK) lh[t] = 0;
    __syncthreads();
    int stride = gridDim.x * 256;
    for (int i = blockIdx.x * 256 + t; i < E + NN; i += stride) {
        int d = (i < E) ? ei[E + i] : (i - E);
        atomicAdd(&lh[d >> BSH], 1);
    }
    __syncthreads();
    if (t < NBUCK && lh[t]) atomicAdd(&bsize[t], lh[t]);
}

__global__ __launch_bounds__(256) void bucket_scan_kernel(
    const int* __restrict__ bsize, int* bbase, int* bcursor)
{
    __shared__ int sm[256];
    int t = threadIdx.x;
    int v = (t < NBUCK) ? bsize[t] : 0;
    sm[t] = v;
    __syncthreads();
    #pragma unroll
    for (int off = 1; off < 256; off <<= 1) {
        int x = (t >= off) ? sm[t - off] : 0;
        __syncthreads();
        sm[t] += x;
        __syncthreads();
    }
    if (t < NBUCK) {
        int excl = sm[t] - v;
        bbase[t] = excl;
        bcursor[t] = excl;
    }
    if (t == 255) bbase[NBUCK] = sm[255];
}

__global__ __launch_bounds__(256) void phaseB_kernel(
    const uint* __restrict__ pairs, const int* __restrict__ bbase,
    int* __restrict__ row_ptr, int* __restrict__ colidx, int EP)
{
    __shared__ int nh[BNODES];
    __shared__ int ex[BNODES];
    __shared__ int ss[256];
    __shared__ int img[BCAP];
    int b = blockIdx.x, t = threadIdx.x;
    int node0 = b << BSH;
    int nend = min(NN - node0, BNODES);
    int pb = bbase[b], pe = bbase[b + 1];
    int span = pe - pb;
    for (int j = t; j < BNODES; j += 256) nh[j] = 0;
    __syncthreads();
    for (int i = t; i < span; i += 256)
        atomicAdd(&nh[pairs[pb + i] >> 17], 1);
    __syncthreads();
    int v0 = nh[2 * t], v1 = nh[2 * t + 1];
    int psc = v0 + v1;
    ss[t] = psc;
    __syncthreads();
    #pragma unroll
    for (int off = 1; off < 256; off <<= 1) {
        int x = (t >= off) ? ss[t - off] : 0;
        __syncthreads();
        ss[t] += x;
        __syncthreads();
    }
    int ep = ss[t] - psc;
    ex[2 * t] = ep;
    ex[2 * t + 1] = ep + v0;
    __syncthreads();
    for (int j = t; j < nend; j += 256) row_ptr[node0 + j] = pb + ex[j];
    if (b == NBUCK - 1 && t == 0) row_ptr[NN] = EP;
    for (int j = t; j < BNODES; j += 256) nh[j] = ex[j];   // reuse as cursors
    __syncthreads();
    if (span <= BCAP) {
        for (int i = t; i < span; i += 256) {
            uint p = pairs[pb + i];
            int pos = atomicAdd(&nh[p >> 17], 1);
            img[pos] = (int)(p & SRCMASK);
        }
        __syncthreads();
        for (int i = t; i < span; i += 256) colidx[pb + i] = img[i];
    } else {
        for (int i = t; i < span; i += 256) {
            uint p = pairs[pb + i];
            int pos = atomicAdd(&nh[p >> 17], 1);
            colidx[pb + pos] = (int)(p & SRCMASK);
        }
    }
}

// ======================= final aggr + FC(128->10) + log_softmax =======================
__global__ __launch_bounds__(256) void aggr_fc_kernel(
    const int* __restrict__ row_ptr, const int* __restrict__ colidx,
    const ushort* __restrict__ hbf, const float* __restrict__ al_s,
    const float* __restrict__ al_d, const float* __restrict__ bias,
    const float* __restrict__ fcW, const float* __restrict__ fcb,
    float* __restrict__ logout)
{
    __shared__ float WT[10][FEAT];
    __shared__ float bl[10];
    int t = threadIdx.x;
    for (int i = t; i < FEAT * 10; i += 256) {
        int k = i / 10, c = i % 10;
        WT[c][k] = fcW[i];
    }
    if (t < 10) bl[t] = fcb[t];
    __syncthreads();

    int node = blockIdx.x * 16 + (t >> 4);
    int lane = t & 15;
    float o[8];
    aggr_node(row_ptr, colidx, hbf, al_s, al_d, bias, node, lane, o);

    float lg[10];
    #pragma unroll
    for (int c = 0; c < 10; ++c) {
        const float* wr = &WT[c][lane * 8];
        float4 wa = *(const float4*)(wr);
        float4 wb = *(const float4*)(wr + 4);
        float acc = fmaf(o[0], wa.x, fmaf(o[1], wa.y, fmaf(o[2], wa.z, o[3] * wa.w)));
        acc = fmaf(o[4], wb.x, fmaf(o[5], wb.y, fmaf(o[6], wb.z, fmaf(o[7], wb.w, acc))));
        lg[c] = acc;
    }
    #pragma unroll
    for (int c = 0; c < 10; ++c) {
        lg[c] += __shfl_xor(lg[c], 1, 16);
        lg[c] += __shfl_xor(lg[c], 2, 16);
        lg[c] += __shfl_xor(lg[c], 4, 16);
        lg[c] += __shfl_xor(lg[c], 8, 16);
    }
    if (lane == 0) {
        float mx = -1e30f;
        #pragma unroll
        for (int c = 0; c < 10; ++c) { lg[c] += bl[c]; mx = fmaxf(mx, lg[c]); }
        float se = 0.f;
        #pragma unroll
        for (int c = 0; c < 10; ++c) se += __expf(lg[c] - mx);
        float lse = mx + __logf(se);
        float2* op = (float2*)(logout + (size_t)node * 10);
        #pragma unroll
        for (int c = 0; c < 5; ++c)
            op[c] = make_float2(lg[2*c] - lse, lg[2*c + 1] - lse);
    }
}

extern "C" void kernel_launch(void* const* d_in, const int* in_sizes, int n_in,
                              void* d_out, int out_size, void* d_ws, size_t ws_size,
                              hipStream_t stream)
{
    const float* x   = (const float*)d_in[0];
    const int*   ei  = (const int*)d_in[1];
    const float* W[3]   = {(const float*)d_in[2], (const float*)d_in[6],  (const float*)d_in[10]};
    const float* asr[3] = {(const float*)d_in[3], (const float*)d_in[7],  (const float*)d_in[11]};
    const float* ads[3] = {(const float*)d_in[4], (const float*)d_in[8],  (const float*)d_in[12]};
    const float* bs[3]  = {(const float*)d_in[5], (const float*)d_in[9],  (const float*)d_in[13]};
    const float* fcW = (const float*)d_in[14];
    const float* fcb = (const float*)d_in[15];
    const int E  = in_sizes[1] / 2;
    const int EP = E + NN;

    // workspace layout (ping-pong h/al buffers for fused layers)
    ushort* hbfA = (ushort*)d_ws;                       // [NN*FEAT] bf16
    ushort* hbfB = hbfA + (size_t)NN * FEAT;            // [NN*FEAT] bf16
    float* alsA  = (float*)(hbfB + (size_t)NN * FEAT);  // [NN*4]
    float* aldA  = alsA + (size_t)NN * NHEAD;           // [NN*4]
    float* alsB  = aldA + (size_t)NN * NHEAD;           // [NN*4]
    float* aldB  = alsB + (size_t)NN * NHEAD;           // [NN*4]
    int* row_ptr = (int*)(aldB + (size_t)NN * NHEAD);   // [NN+1]
    int* bsize   = row_ptr + NN + 1;                    // [NBUCK]
    int* bbase   = bsize + NBUCK;                       // [NBUCK+1]
    int* bcursor = bbase + NBUCK + 1;                   // [NBUCK]
    uint* pairs  = (uint*)(bcursor + NBUCK);            // [EP] packed
    int* colidx  = (int*)(pairs + (size_t)EP);          // [EP]

    const int pab = (EP + 256 * PA_EPT - 1) / (256 * PA_EPT);

    // ---- CSR build head ----
    hipMemsetAsync(bsize, 0, NBUCK * sizeof(int), stream);
    bucket_hist_kernel<<<1024, 256, 0, stream>>>(ei, E, bsize);
    bucket_scan_kernel<<<1, 256, 0, stream>>>(bsize, bbase, bcursor);

    // ---- layer 0 gemm (fp32 in) overlapped with CSR phase A ----
    gemm0_phaseA_kernel<<<GEMMB + pab, 256, 0, stream>>>(
        x, W[0], asr[0], ads[0], hbfA, alsA, aldA, ei, E, bcursor, pairs);
    phaseB_kernel<<<NBUCK, 256, 0, stream>>>(pairs, bbase, row_ptr, colidx, EP);

    // ---- fused aggr(L0)+gemm(L1), aggr(L1)+gemm(L2) ----
    aggr_gemm_fused_kernel<<<GEMMB, 256, 0, stream>>>(
        row_ptr, colidx, hbfA, alsA, aldA, bs[0], W[1], asr[1], ads[1],
        hbfB, alsB, aldB);
    aggr_gemm_fused_kernel<<<GEMMB, 256, 0, stream>>>(
        row_ptr, colidx, hbfB, alsB, aldB, bs[1], W[2], asr[2], ads[2],
        hbfA, alsA, aldA);

    // ---- final aggr + FC + log_softmax ----
    aggr_fc_kernel<<<(NN + 15) / 16, 256, 0, stream>>>(
        row_ptr, colidx, hbfA, alsA, aldA, bs[2], fcW, fcb, (float*)d_out);
}

// Round 5
// 496.863 us; speedup vs baseline: 1.0043x; 1.0043x over previous
//
#include <hip/hip_runtime.h>
#include <math.h>

#define NN 100000
#define FEAT 128
#define NHEAD 4
#define BSH 9                      // 512 nodes per bucket
#define BNODES 512
#define NBUCK 196                  // ceil(NN / 512)
#define BCAP 16384                 // colidx LDS image capacity (avg span ~8700)
#define PA_EPT 16                  // phase-A edges per thread
#define GTILES 6250                // 100000 / 16
#define GEMMB 1563                 // gemm/fused grid blocks: 1 tile per wave
#define HSTRIDE 136                // h-tile row stride in ushorts (bank-conflict pad)
#define HISTB 1024                 // hist blocks; W-prep blocks follow
#define WPREPB 192                 // 3 matrices * 64 blocks
#define SRCMASK 0x1FFFF            // low 17 bits: src id (NN < 2^17)

typedef unsigned int uint;
typedef unsigned short ushort;
typedef __attribute__((ext_vector_type(8))) short short8;
typedef __attribute__((ext_vector_type(4))) float fx4;

__device__ __forceinline__ float lrelu(float v) { return v > 0.f ? v : 0.2f * v; }

__device__ __forceinline__ ushort f2bf(float f) {          // RNE bf16
    uint u = __float_as_uint(f);
    return (ushort)((u + 0x7fffu + ((u >> 16) & 1u)) >> 16);
}
__device__ __forceinline__ float bf_lo(uint u) { return __uint_as_float(u << 16); }
__device__ __forceinline__ float bf_hi(uint u) { return __uint_as_float(u & 0xffff0000u); }

__device__ __forceinline__ short8 pack8f(const float* p) {
    float4 a = *(const float4*)p, b = *(const float4*)(p + 4);
    short8 v;
    v[0] = (short)f2bf(a.x); v[1] = (short)f2bf(a.y);
    v[2] = (short)f2bf(a.z); v[3] = (short)f2bf(a.w);
    v[4] = (short)f2bf(b.x); v[5] = (short)f2bf(b.y);
    v[6] = (short)f2bf(b.z); v[7] = (short)f2bf(b.w);
    return v;
}

// ======================= shared aggr core =======================
#define AGGR_STEP(hv, wgt)                                                    \
    a0 = fmaf(wgt, bf_lo(hv.x), a0); a1 = fmaf(wgt, bf_hi(hv.x), a1);        \
    a2 = fmaf(wgt, bf_lo(hv.y), a2); a3 = fmaf(wgt, bf_hi(hv.y), a3);        \
    a4 = fmaf(wgt, bf_lo(hv.z), a4); a5 = fmaf(wgt, bf_hi(hv.z), a5);        \
    a6 = fmaf(wgt, bf_lo(hv.w), a6); a7 = fmaf(wgt, bf_hi(hv.w), a7);

#define PROC4(cv)                                                             \
    {                                                                         \
        int s0 = cv.x, s1 = cv.y, s2 = cv.z, s3 = cv.w;                       \
        float w0 = __expf(lrelu(al_s[s0*4 + head] + ald_h));                  \
        float w1 = __expf(lrelu(al_s[s1*4 + head] + ald_h));                  \
        float w2 = __expf(lrelu(al_s[s2*4 + head] + ald_h));                  \
        float w3 = __expf(lrelu(al_s[s3*4 + head] + ald_h));                  \
        uint4 h0 = ((const uint4*)(hbf + (size_t)s0 * FEAT))[lane];           \
        uint4 h1 = ((const uint4*)(hbf + (size_t)s1 * FEAT))[lane];           \
        uint4 h2 = ((const uint4*)(hbf + (size_t)s2 * FEAT))[lane];           \
        uint4 h3 = ((const uint4*)(hbf + (size_t)s3 * FEAT))[lane];           \
        ssum += (w0 + w1) + (w2 + w3);                                        \
        AGGR_STEP(h0, w0) AGGR_STEP(h1, w1) AGGR_STEP(h2, w2) AGGR_STEP(h3, w3) \
    }

#define PROC8(cva, cvb)                                                       \
    {                                                                         \
        int s0 = cva.x, s1 = cva.y, s2 = cva.z, s3 = cva.w;                   \
        int s4 = cvb.x, s5 = cvb.y, s6 = cvb.z, s7 = cvb.w;                   \
        uint4 h0 = ((const uint4*)(hbf + (size_t)s0 * FEAT))[lane];           \
        uint4 h1 = ((const uint4*)(hbf + (size_t)s1 * FEAT))[lane];           \
        uint4 h2 = ((const uint4*)(hbf + (size_t)s2 * FEAT))[lane];           \
        uint4 h3 = ((const uint4*)(hbf + (size_t)s3 * FEAT))[lane];           \
        uint4 h4 = ((const uint4*)(hbf + (size_t)s4 * FEAT))[lane];           \
        uint4 h5 = ((const uint4*)(hbf + (size_t)s5 * FEAT))[lane];           \
        uint4 h6 = ((const uint4*)(hbf + (size_t)s6 * FEAT))[lane];           \
        uint4 h7 = ((const uint4*)(hbf + (size_t)s7 * FEAT))[lane];           \
        float w0 = __expf(lrelu(al_s[s0*4 + head] + ald_h));                  \
        float w1 = __expf(lrelu(al_s[s1*4 + head] + ald_h));                  \
        float w2 = __expf(lrelu(al_s[s2*4 + head] + ald_h));                  \
        float w3 = __expf(lrelu(al_s[s3*4 + head] + ald_h));                  \
        float w4 = __expf(lrelu(al_s[s4*4 + head] + ald_h));                  \
        float w5 = __expf(lrelu(al_s[s5*4 + head] + ald_h));                  \
        float w6 = __expf(lrelu(al_s[s6*4 + head] + ald_h));                  \
        float w7 = __expf(lrelu(al_s[s7*4 + head] + ald_h));                  \
        ssum += ((w0 + w1) + (w2 + w3)) + ((w4 + w5) + (w6 + w7));            \
        AGGR_STEP(h0, w0) AGGR_STEP(h1, w1) AGGR_STEP(h2, w2) AGGR_STEP(h3, w3) \
        AGGR_STEP(h4, w4) AGGR_STEP(h5, w5) AGGR_STEP(h6, w6) AGGR_STEP(h7, w7) \
    }

__device__ __forceinline__ void aggr_node(
    const int* __restrict__ row_ptr, const int* __restrict__ colidx,
    const ushort* __restrict__ hbf, const float* __restrict__ al_s,
    const float* __restrict__ al_d, const float* __restrict__ bias,
    int node, int lane, float* __restrict__ o)
{
    const int head = lane >> 2;
    float ald_h = al_d[node * 4 + head];
    int beg = row_ptr[node], end = row_ptr[node + 1];

    float ssum = 0.f;
    float a0=0.f,a1=0.f,a2=0.f,a3=0.f,a4=0.f,a5=0.f,a6=0.f,a7=0.f;

    int p = beg;
    int4 ca, cb;
    if (p + 8 <= end) {
        ca = *(const int4*)&colidx[p];
        cb = *(const int4*)&colidx[p + 4];
    }
    while (p + 16 <= end) {
        int4 na = *(const int4*)&colidx[p + 8];    // prefetch next 8-batch
        int4 nb = *(const int4*)&colidx[p + 12];
        PROC8(ca, cb)
        ca = na; cb = nb;
        p += 8;
    }
    if (p + 8 <= end) { PROC8(ca, cb) p += 8; }
    if (p + 4 <= end) {
        int4 c4 = *(const int4*)&colidx[p];
        PROC4(c4)
        p += 4;
    }
    for (; p < end; ++p) {
        int sn = colidx[p];
        float wq = __expf(lrelu(al_s[sn*4 + head] + ald_h));
        uint4 hv = ((const uint4*)(hbf + (size_t)sn * FEAT))[lane];
        ssum += wq;
        AGGR_STEP(hv, wq)
    }

    float inv = 1.f / (ssum + 1e-16f);
    const float* bp = bias + lane * 8;
    float oo[8] = {a0,a1,a2,a3,a4,a5,a6,a7};
    #pragma unroll
    for (int k = 0; k < 8; ++k) {
        float v = oo[k] * inv + bp[k];
        o[k] = v > 0.f ? v : __expf(v) - 1.f;
    }
}

// ======================= gemm epilogue (shared) =======================
__device__ __forceinline__ void gemm_epilogue(
    fx4* acc, const float* __restrict__ a_src, const float* __restrict__ a_dst,
    ushort* __restrict__ hbf_out, float* __restrict__ al_s_out,
    float* __restrict__ al_d_out, int n0, int node_l, int q)
{
    float ps[4] = {0.f, 0.f, 0.f, 0.f};
    float pd[4] = {0.f, 0.f, 0.f, 0.f};
    #pragma unroll
    for (int mt = 0; mt < 8; ++mt) {
        float4 as4 = *(const float4*)(a_src + mt * 16 + q * 4);
        float4 ad4 = *(const float4*)(a_dst + mt * 16 + q * 4);
        ps[mt >> 1] += acc[mt][0] * as4.x + acc[mt][1] * as4.y + acc[mt][2] * as4.z + acc[mt][3] * as4.w;
        pd[mt >> 1] += acc[mt][0] * ad4.x + acc[mt][1] * ad4.y + acc[mt][2] * ad4.z + acc[mt][3] * ad4.w;
        ushort4 hv;
        hv.x = f2bf(acc[mt][0]); hv.y = f2bf(acc[mt][1]);
        hv.z = f2bf(acc[mt][2]); hv.w = f2bf(acc[mt][3]);
        *(ushort4*)(hbf_out + (size_t)(n0 + node_l) * FEAT + mt * 16 + q * 4) = hv;
    }
    #pragma unroll
    for (int h = 0; h < 4; ++h) {
        ps[h] += __shfl_xor(ps[h], 16); ps[h] += __shfl_xor(ps[h], 32);
        pd[h] += __shfl_xor(pd[h], 16); pd[h] += __shfl_xor(pd[h], 32);
    }
    float vs = (q == 0) ? ps[0] : (q == 1) ? ps[1] : (q == 2) ? ps[2] : ps[3];
    float vd = (q == 0) ? pd[0] : (q == 1) ? pd[1] : (q == 2) ? pd[2] : pd[3];
    al_s_out[(n0 + node_l) * 4 + q] = vs;
    al_d_out[(n0 + node_l) * 4 + q] = vd;
}

// ======================= gemm0: fp32 input, A-frags from global bf16 W =======================
// r16: barrier-free, zero LDS — A-fragments read from pre-converted fragment-
// ordered global wb (32 KB, L2-hot, coalesced).
__device__ __forceinline__ void gemm0_body(
    const float* __restrict__ x, const ushort* __restrict__ wb,
    const float* __restrict__ a_src, const float* __restrict__ a_dst,
    ushort* __restrict__ hbf, float* __restrict__ al_s, float* __restrict__ al_d,
    int bid)
{
    const int t = threadIdx.x;
    const int lane = t & 63;
    const int node_l = lane & 15, q = lane >> 4;
    const int tile = bid * 4 + (t >> 6);
    if (tile >= GTILES) return;
    const int n0 = tile * 16;

    const float* rf = x + (size_t)(n0 + node_l) * FEAT + q * 8;
    short8 b0 = pack8f(rf);
    short8 b1 = pack8f(rf + 32);
    short8 b2 = pack8f(rf + 64);
    short8 b3 = pack8f(rf + 96);

    fx4 zero = {0.f, 0.f, 0.f, 0.f};
    fx4 acc[8];
    #pragma unroll
    for (int mt = 0; mt < 8; ++mt) acc[mt] = zero;
    #pragma unroll
    for (int kt = 0; kt < 4; ++kt) {
        short8 b = (kt == 0) ? b0 : (kt == 1) ? b1 : (kt == 2) ? b2 : b3;
        #pragma unroll
        for (int mt = 0; mt < 8; ++mt) {
            short8 a = *(const short8*)&wb[((mt * 4 + kt) * 64 + lane) * 8];
            acc[mt] = __builtin_amdgcn_mfma_f32_16x16x32_bf16(a, b, acc[mt], 0, 0, 0);
        }
    }
    gemm_epilogue(acc, a_src, a_dst, hbf, al_s, al_d, n0, node_l, q);
}

// ---- phase-A body: bucket-binned (dst,src) pair scatter ----
__device__ __forceinline__ void phaseA_body(
    const int* __restrict__ ei, int E, int* bcursor, uint* __restrict__ pairs, int bid)
{
    __shared__ int lh[NBUCK], lb[NBUCK];
    int t = threadIdx.x;
    if (t < NBUCK) lh[t] = 0;
    __syncthreads();
    int base = bid * (256 * PA_EPT) + t;
    int s[PA_EPT], d[PA_EPT];
    #pragma unroll
    for (int k = 0; k < PA_EPT; ++k) {
        int i = base + k * 256;
        if (i < E)            { s[k] = ei[i]; d[k] = ei[E + i]; }
        else if (i < E + NN)  { s[k] = i - E; d[k] = s[k]; }
        else                  { s[k] = 0; d[k] = -1; }
        if (d[k] >= 0) atomicAdd(&lh[d[k] >> BSH], 1);
    }
    __syncthreads();
    if (t < NBUCK) {
        int c = lh[t];
        lb[t] = c ? atomicAdd(&bcursor[t], c) : 0;
        lh[t] = 0;
    }
    __syncthreads();
    #pragma unroll
    for (int k = 0; k < PA_EPT; ++k) {
        if (d[k] >= 0) {
            int b = d[k] >> BSH;
            int off = atomicAdd(&lh[b], 1);
            pairs[lb[b] + off] = ((uint)(d[k] & (BNODES - 1)) << 17) | (uint)s[k];
        }
    }
}

// ---- fused: gemm layer 0 || CSR phase A (data-independent) ----
__global__ __launch_bounds__(256, 2) void gemm0_phaseA_kernel(
    const float* __restrict__ x, const ushort* __restrict__ w0b,
    const float* __restrict__ a_src, const float* __restrict__ a_dst,
    ushort* __restrict__ hbf, float* __restrict__ al_s, float* __restrict__ al_d,
    const int* __restrict__ ei, int E, int* bcursor, uint* __restrict__ pairs)
{
    if (blockIdx.x < GEMMB)
        gemm0_body(x, w0b, a_src, a_dst, hbf, al_s, al_d, blockIdx.x);
    else
        phaseA_body(ei, E, bcursor, pairs, blockIdx.x - GEMMB);
}

// ======================= fused aggr(L) + gemm(L+1), v2 =======================
// r16: barrier-free. Per wave: aggr 16 nodes -> HS (wave-local LDS) -> B-frags
// from HS, A-frags from global bf16 wb (L2-hot) -> MFMA -> epilogue. No WA, no
// __syncthreads: waves desync so MFMA overlaps other waves' gathers. LDS 17 KB.
__global__ __launch_bounds__(256, 4) void aggr_gemm_fused_kernel(
    const int* __restrict__ row_ptr, const int* __restrict__ colidx,
    const ushort* __restrict__ hbf_in, const float* __restrict__ al_s_in,
    const float* __restrict__ al_d_in, const float* __restrict__ bias,
    const ushort* __restrict__ wb, const float* __restrict__ a_src,
    const float* __restrict__ a_dst,
    ushort* __restrict__ hbf_out, float* __restrict__ al_s_out,
    float* __restrict__ al_d_out)
{
    __shared__ __align__(16) ushort HS[4][16 * HSTRIDE];   // 17 KiB, per-wave
    const int t = threadIdx.x;
    const int wv = t >> 6, lane = t & 63;
    const int tile = blockIdx.x * 4 + wv;
    if (tile >= GTILES) return;
    const int n0 = tile * 16;
    const int ng = lane >> 4, l16 = lane & 15;

    // ---- aggr phase: 16 nodes, 4 per iteration (16 lanes each) ----
    #pragma unroll 1
    for (int it = 0; it < 4; ++it) {
        int node = n0 + it * 4 + ng;
        float o[8];
        aggr_node(row_ptr, colidx, hbf_in, al_s_in, al_d_in, bias, node, l16, o);
        uint4 u;
        u.x = (uint)f2bf(o[0]) | ((uint)f2bf(o[1]) << 16);
        u.y = (uint)f2bf(o[2]) | ((uint)f2bf(o[3]) << 16);
        u.z = (uint)f2bf(o[4]) | ((uint)f2bf(o[5]) << 16);
        u.w = (uint)f2bf(o[6]) | ((uint)f2bf(o[7]) << 16);
        *(uint4*)&HS[wv][(it * 4 + ng) * HSTRIDE + l16 * 8] = u;
    }
    __builtin_amdgcn_sched_barrier(0);   // keep A-frag loads below the gather loop

    // ---- gemm phase: B from HS (wave-local), A from global wb ----
    const int node_l = l16, q = ng;
    short8 b0 = *(const short8*)&HS[wv][node_l * HSTRIDE +      q * 8];
    short8 b1 = *(const short8*)&HS[wv][node_l * HSTRIDE + 32 + q * 8];
    short8 b2 = *(const short8*)&HS[wv][node_l * HSTRIDE + 64 + q * 8];
    short8 b3 = *(const short8*)&HS[wv][node_l * HSTRIDE + 96 + q * 8];

    fx4 zero = {0.f, 0.f, 0.f, 0.f};
    fx4 acc[8];
    #pragma unroll
    for (int mt = 0; mt < 8; ++mt) acc[mt] = zero;
    #pragma unroll
    for (int kt = 0; kt < 4; ++kt) {
        short8 b = (kt == 0) ? b0 : (kt == 1) ? b1 : (kt == 2) ? b2 : b3;
        #pragma unroll
        for (int mt = 0; mt < 8; ++mt) {
            short8 a = *(const short8*)&wb[((mt * 4 + kt) * 64 + lane) * 8];
            acc[mt] = __builtin_amdgcn_mfma_f32_16x16x32_bf16(a, b, acc[mt], 0, 0, 0);
        }
    }
    gemm_epilogue(acc, a_src, a_dst, hbf_out, al_s_out, al_d_out, n0, node_l, q);
}

// ======================= CSR build =======================

// hist + W->bf16 fragment-order prep fused (independent work, same launch)
__global__ __launch_bounds__(256) void hist_wprep_kernel(
    const int* __restrict__ ei, int E, int* bsize,
    const float* __restrict__ W0, const float* __restrict__ W1,
    const float* __restrict__ W2,
    ushort* __restrict__ wb0, ushort* __restrict__ wb1, ushort* __restrict__ wb2)
{
    int t = threadIdx.x;
    if (blockIdx.x < HISTB) {
        __shared__ int lh[NBUCK];
        if (t < NBUCK) lh[t] = 0;
        __syncthreads();
        int stride = HISTB * 256;
        for (int i = blockIdx.x * 256 + t; i < E + NN; i += stride) {
            int d = (i < E) ? ei[E + i] : (i - E);
            atomicAdd(&lh[d >> BSH], 1);
        }
        __syncthreads();
        if (t < NBUCK && lh[t]) atomicAdd(&bsize[t], lh[t]);
    } else {
        int b = blockIdx.x - HISTB;          // 0..WPREPB-1
        int mat = b >> 6;
        int idx = ((b & 63) << 8) | t;       // 0..16383
        const float* Wm = (mat == 0) ? W0 : (mat == 1) ? W1 : W2;
        ushort* wbm     = (mat == 0) ? wb0 : (mat == 1) ? wb1 : wb2;
        int k = idx >> 7, m = idx & 127;
        int mt = m >> 4, kt = k >> 5, qq = (k >> 3) & 3, j = k & 7;
        int ln = qq * 16 + (m & 15);
        wbm[((mt * 4 + kt) * 64 + ln) * 8 + j] = f2bf(Wm[idx]);
    }
}

__global__ __launch_bounds__(256) void bucket_scan_kernel(
    const int* __restrict__ bsize, int* bbase, int* bcursor)
{
    __shared__ int sm[256];
    int t = threadIdx.x;
    int v = (t < NBUCK) ? bsize[t] : 0;
    sm[t] = v;
    __syncthreads();
    #pragma unroll
    for (int off = 1; off < 256; off <<= 1) {
        int x = (t >= off) ? sm[t - off] : 0;
        __syncthreads();
        sm[t] += x;
        __syncthreads();
    }
    if (t < NBUCK) {
        int excl = sm[t] - v;
        bbase[t] = excl;
        bcursor[t] = excl;
    }
    if (t == 255) bbase[NBUCK] = sm[255];
}

__global__ __launch_bounds__(256) void phaseB_kernel(
    const uint* __restrict__ pairs, const int* __restrict__ bbase,
    int* __restrict__ row_ptr, int* __restrict__ colidx, int EP)
{
    __shared__ int nh[BNODES];
    __shared__ int ex[BNODES];
    __shared__ int ss[256];
    __shared__ int img[BCAP];
    int b = blockIdx.x, t = threadIdx.x;
    int node0 = b << BSH;
    int nend = min(NN - node0, BNODES);
    int pb = bbase[b], pe = bbase[b + 1];
    int span = pe - pb;
    for (int j = t; j < BNODES; j += 256) nh[j] = 0;
    __syncthreads();
    for (int i = t; i < span; i += 256)
        atomicAdd(&nh[pairs[pb + i] >> 17], 1);
    __syncthreads();
    int v0 = nh[2 * t], v1 = nh[2 * t + 1];
    int psc = v0 + v1;
    ss[t] = psc;
    __syncthreads();
    #pragma unroll
    for (int off = 1; off < 256; off <<= 1) {
        int x = (t >= off) ? ss[t - off] : 0;
        __syncthreads();
        ss[t] += x;
        __syncthreads();
    }
    int ep = ss[t] - psc;
    ex[2 * t] = ep;
    ex[2 * t + 1] = ep + v0;
    __syncthreads();
    for (int j = t; j < nend; j += 256) row_ptr[node0 + j] = pb + ex[j];
    if (b == NBUCK - 1 && t == 0) row_ptr[NN] = EP;
    for (int j = t; j < BNODES; j += 256) nh[j] = ex[j];   // reuse as cursors
    __syncthreads();
    if (span <= BCAP) {
        for (int i = t; i < span; i += 256) {
            uint p = pairs[pb + i];
            int pos = atomicAdd(&nh[p >> 17], 1);
            img[pos] = (int)(p & SRCMASK);
        }
        __syncthreads();
        for (int i = t; i < span; i += 256) colidx[pb + i] = img[i];
    } else {
        for (int i = t; i < span; i += 256) {
            uint p = pairs[pb + i];
            int pos = atomicAdd(&nh[p >> 17], 1);
            colidx[pb + pos] = (int)(p & SRCMASK);
        }
    }
}

// ======================= final aggr + FC(128->10) + log_softmax =======================
__global__ __launch_bounds__(256) void aggr_fc_kernel(
    const int* __restrict__ row_ptr, const int* __restrict__ colidx,
    const ushort* __restrict__ hbf, const float* __restrict__ al_s,
    const float* __restrict__ al_d, const float* __restrict__ bias,
    const float* __restrict__ fcW, const float* __restrict__ fcb,
    float* __restrict__ logout)
{
    __shared__ float WT[10][FEAT];
    __shared__ float bl[10];
    int t = threadIdx.x;
    for (int i = t; i < FEAT * 10; i += 256) {
        int k = i / 10, c = i % 10;
        WT[c][k] = fcW[i];
    }
    if (t < 10) bl[t] = fcb[t];
    __syncthreads();

    int node = blockIdx.x * 16 + (t >> 4);
    int lane = t & 15;
    float o[8];
    aggr_node(row_ptr, colidx, hbf, al_s, al_d, bias, node, lane, o);

    float lg[10];
    #pragma unroll
    for (int c = 0; c < 10; ++c) {
        const float* wr = &WT[c][lane * 8];
        float4 wa = *(const float4*)(wr);
        float4 wb = *(const float4*)(wr + 4);
        float acc = fmaf(o[0], wa.x, fmaf(o[1], wa.y, fmaf(o[2], wa.z, o[3] * wa.w)));
        acc = fmaf(o[4], wb.x, fmaf(o[5], wb.y, fmaf(o[6], wb.z, fmaf(o[7], wb.w, acc))));
        lg[c] = acc;
    }
    #pragma unroll
    for (int c = 0; c < 10; ++c) {
        lg[c] += __shfl_xor(lg[c], 1, 16);
        lg[c] += __shfl_xor(lg[c], 2, 16);
        lg[c] += __shfl_xor(lg[c], 4, 16);
        lg[c] += __shfl_xor(lg[c], 8, 16);
    }
    if (lane == 0) {
        float mx = -1e30f;
        #pragma unroll
        for (int c = 0; c < 10; ++c) { lg[c] += bl[c]; mx = fmaxf(mx, lg[c]); }
        float se = 0.f;
        #pragma unroll
        for (int c = 0; c < 10; ++c) se += __expf(lg[c] - mx);
        float lse = mx + __logf(se);
        float2* op = (float2*)(logout + (size_t)node * 10);
        #pragma unroll
        for (int c = 0; c < 5; ++c)
            op[c] = make_float2(lg[2*c] - lse, lg[2*c + 1] - lse);
    }
}

extern "C" void kernel_launch(void* const* d_in, const int* in_sizes, int n_in,
                              void* d_out, int out_size, void* d_ws, size_t ws_size,
                              hipStream_t stream)
{
    const float* x   = (const float*)d_in[0];
    const int*   ei  = (const int*)d_in[1];
    const float* W[3]   = {(const float*)d_in[2], (const float*)d_in[6],  (const float*)d_in[10]};
    const float* asr[3] = {(const float*)d_in[3], (const float*)d_in[7],  (const float*)d_in[11]};
    const float* ads[3] = {(const float*)d_in[4], (const float*)d_in[8],  (const float*)d_in[12]};
    const float* bs[3]  = {(const float*)d_in[5], (const float*)d_in[9],  (const float*)d_in[13]};
    const float* fcW = (const float*)d_in[14];
    const float* fcb = (const float*)d_in[15];
    const int E  = in_sizes[1] / 2;
    const int EP = E + NN;

    // workspace layout (ping-pong h/al buffers; wb = fragment-ordered bf16 W)
    ushort* hbfA = (ushort*)d_ws;                       // [NN*FEAT] bf16
    ushort* hbfB = hbfA + (size_t)NN * FEAT;            // [NN*FEAT] bf16
    float* alsA  = (float*)(hbfB + (size_t)NN * FEAT);  // [NN*4]
    float* aldA  = alsA + (size_t)NN * NHEAD;           // [NN*4]
    float* alsB  = aldA + (size_t)NN * NHEAD;           // [NN*4]
    float* aldB  = alsB + (size_t)NN * NHEAD;           // [NN*4]
    int* row_ptr = (int*)(aldB + (size_t)NN * NHEAD);   // [NN+1]
    int* bsize   = row_ptr + NN + 1;                    // [NBUCK]
    int* bbase   = bsize + NBUCK;                       // [NBUCK+1]
    int* bcursor = bbase + NBUCK + 1;                   // [NBUCK]
    uintptr_t pw = ((uintptr_t)(bcursor + NBUCK) + 15) & ~(uintptr_t)15;
    ushort* wb0  = (ushort*)pw;                         // [128*128] bf16, frag-ordered
    ushort* wb1  = wb0 + FEAT * FEAT;
    ushort* wb2  = wb1 + FEAT * FEAT;
    uint* pairs  = (uint*)(wb2 + FEAT * FEAT);          // [EP] packed
    int* colidx  = (int*)(pairs + (size_t)EP);          // [EP]

    const int pab = (EP + 256 * PA_EPT - 1) / (256 * PA_EPT);

    // ---- CSR build head + W prep ----
    hipMemsetAsync(bsize, 0, NBUCK * sizeof(int), stream);
    hist_wprep_kernel<<<HISTB + WPREPB, 256, 0, stream>>>(
        ei, E, bsize, W[0], W[1], W[2], wb0, wb1, wb2);
    bucket_scan_kernel<<<1, 256, 0, stream>>>(bsize, bbase, bcursor);

    // ---- layer 0 gemm (fp32 in, barrier-free) overlapped with CSR phase A ----
    gemm0_phaseA_kernel<<<GEMMB + pab, 256, 0, stream>>>(
        x, wb0, asr[0], ads[0], hbfA, alsA, aldA, ei, E, bcursor, pairs);
    phaseB_kernel<<<NBUCK, 256, 0, stream>>>(pairs, bbase, row_ptr, colidx, EP);

    // ---- fused aggr(L0)+gemm(L1), aggr(L1)+gemm(L2) ----
    aggr_gemm_fused_kernel<<<GEMMB, 256, 0, stream>>>(
        row_ptr, colidx, hbfA, alsA, aldA, bs[0], wb1, asr[1], ads[1],
        hbfB, alsB, aldB);
    aggr_gemm_fused_kernel<<<GEMMB, 256, 0, stream>>>(
        row_ptr, colidx, hbfB, alsB, aldB, bs[1], wb2, asr[2], ads[2],
        hbfA, alsA, aldA);

    // ---- final aggr + FC + log_softmax ----
    aggr_fc_kernel<<<(NN + 15) / 16, 256, 0, stream>>>(
        row_ptr, colidx, hbfA, alsA, aldA, bs[2], fcW, fcb, (float*)d_out);
}

// Round 6
// 459.153 us; speedup vs baseline: 1.0868x; 1.0821x over previous
//
#include <hip/hip_runtime.h>
#include <math.h>

#define NN 100000
#define FEAT 128
#define NHEAD 4
#define BSH 9                      // 512 nodes per bucket
#define BNODES 512
#define NBUCK 196                  // ceil(NN / 512)
#define BCAP 16384                 // colidx LDS image capacity (avg span ~8700)
#define PA_EPT 16                  // phase-A edges per thread
#define GTILES 6250                // 100000 / 16
#define GEMMB 1563                 // gemm/fused grid blocks: 1 tile per wave
#define HSTRIDE 136                // h-tile row stride in ushorts (bank-conflict pad)
#define WPREPB 192                 // 3 matrices * 64 blocks
#define PSH 14                     // strided pairs: 16384 slots per bucket
#define SRCMASK 0x1FFFF            // low 17 bits: src id (NN < 2^17)

typedef unsigned int uint;
typedef unsigned short ushort;
typedef __attribute__((ext_vector_type(8))) short short8;
typedef __attribute__((ext_vector_type(4))) float fx4;

__device__ __forceinline__ float lrelu(float v) { return v > 0.f ? v : 0.2f * v; }

__device__ __forceinline__ ushort f2bf(float f) {          // RNE bf16
    uint u = __float_as_uint(f);
    return (ushort)((u + 0x7fffu + ((u >> 16) & 1u)) >> 16);
}
__device__ __forceinline__ float bf_lo(uint u) { return __uint_as_float(u << 16); }
__device__ __forceinline__ float bf_hi(uint u) { return __uint_as_float(u & 0xffff0000u); }

__device__ __forceinline__ short8 pack8f(const float* p) {
    float4 a = *(const float4*)p, b = *(const float4*)(p + 4);
    short8 v;
    v[0] = (short)f2bf(a.x); v[1] = (short)f2bf(a.y);
    v[2] = (short)f2bf(a.z); v[3] = (short)f2bf(a.w);
    v[4] = (short)f2bf(b.x); v[5] = (short)f2bf(b.y);
    v[6] = (short)f2bf(b.z); v[7] = (short)f2bf(b.w);
    return v;
}

// ======================= shared aggr core =======================
#define AGGR_STEP(hv, wgt)                                                    \
    a0 = fmaf(wgt, bf_lo(hv.x), a0); a1 = fmaf(wgt, bf_hi(hv.x), a1);        \
    a2 = fmaf(wgt, bf_lo(hv.y), a2); a3 = fmaf(wgt, bf_hi(hv.y), a3);        \
    a4 = fmaf(wgt, bf_lo(hv.z), a4); a5 = fmaf(wgt, bf_hi(hv.z), a5);        \
    a6 = fmaf(wgt, bf_lo(hv.w), a6); a7 = fmaf(wgt, bf_hi(hv.w), a7);

#define PROC4(cv)                                                             \
    {                                                                         \
        int s0 = cv.x, s1 = cv.y, s2 = cv.z, s3 = cv.w;                       \
        float w0 = __expf(lrelu(al_s[s0*4 + head] + ald_h));                  \
        float w1 = __expf(lrelu(al_s[s1*4 + head] + ald_h));                  \
        float w2 = __expf(lrelu(al_s[s2*4 + head] + ald_h));                  \
        float w3 = __expf(lrelu(al_s[s3*4 + head] + ald_h));                  \
        uint4 h0 = ((const uint4*)(hbf + (size_t)s0 * FEAT))[lane];           \
        uint4 h1 = ((const uint4*)(hbf + (size_t)s1 * FEAT))[lane];           \
        uint4 h2 = ((const uint4*)(hbf + (size_t)s2 * FEAT))[lane];           \
        uint4 h3 = ((const uint4*)(hbf + (size_t)s3 * FEAT))[lane];           \
        ssum += (w0 + w1) + (w2 + w3);                                        \
        AGGR_STEP(h0, w0) AGGR_STEP(h1, w1) AGGR_STEP(h2, w2) AGGR_STEP(h3, w3) \
    }

#define PROC8(cva, cvb)                                                       \
    {                                                                         \
        int s0 = cva.x, s1 = cva.y, s2 = cva.z, s3 = cva.w;                   \
        int s4 = cvb.x, s5 = cvb.y, s6 = cvb.z, s7 = cvb.w;                   \
        uint4 h0 = ((const uint4*)(hbf + (size_t)s0 * FEAT))[lane];           \
        uint4 h1 = ((const uint4*)(hbf + (size_t)s1 * FEAT))[lane];           \
        uint4 h2 = ((const uint4*)(hbf + (size_t)s2 * FEAT))[lane];           \
        uint4 h3 = ((const uint4*)(hbf + (size_t)s3 * FEAT))[lane];           \
        uint4 h4 = ((const uint4*)(hbf + (size_t)s4 * FEAT))[lane];           \
        uint4 h5 = ((const uint4*)(hbf + (size_t)s5 * FEAT))[lane];           \
        uint4 h6 = ((const uint4*)(hbf + (size_t)s6 * FEAT))[lane];           \
        uint4 h7 = ((const uint4*)(hbf + (size_t)s7 * FEAT))[lane];           \
        float w0 = __expf(lrelu(al_s[s0*4 + head] + ald_h));                  \
        float w1 = __expf(lrelu(al_s[s1*4 + head] + ald_h));                  \
        float w2 = __expf(lrelu(al_s[s2*4 + head] + ald_h));                  \
        float w3 = __expf(lrelu(al_s[s3*4 + head] + ald_h));                  \
        float w4 = __expf(lrelu(al_s[s4*4 + head] + ald_h));                  \
        float w5 = __expf(lrelu(al_s[s5*4 + head] + ald_h));                  \
        float w6 = __expf(lrelu(al_s[s6*4 + head] + ald_h));                  \
        float w7 = __expf(lrelu(al_s[s7*4 + head] + ald_h));                  \
        ssum += ((w0 + w1) + (w2 + w3)) + ((w4 + w5) + (w6 + w7));            \
        AGGR_STEP(h0, w0) AGGR_STEP(h1, w1) AGGR_STEP(h2, w2) AGGR_STEP(h3, w3) \
        AGGR_STEP(h4, w4) AGGR_STEP(h5, w5) AGGR_STEP(h6, w6) AGGR_STEP(h7, w7) \
    }

__device__ __forceinline__ void aggr_node(
    const int* __restrict__ row_ptr, const int* __restrict__ colidx,
    const ushort* __restrict__ hbf, const float* __restrict__ al_s,
    const float* __restrict__ al_d, const float* __restrict__ bias,
    int node, int lane, float* __restrict__ o)
{
    const int head = lane >> 2;
    float ald_h = al_d[node * 4 + head];
    int beg = row_ptr[node], end = row_ptr[node + 1];

    float ssum = 0.f;
    float a0=0.f,a1=0.f,a2=0.f,a3=0.f,a4=0.f,a5=0.f,a6=0.f,a7=0.f;

    int p = beg;
    int4 ca, cb;
    if (p + 8 <= end) {
        ca = *(const int4*)&colidx[p];
        cb = *(const int4*)&colidx[p + 4];
    }
    while (p + 16 <= end) {
        int4 na = *(const int4*)&colidx[p + 8];    // prefetch next 8-batch
        int4 nb = *(const int4*)&colidx[p + 12];
        PROC8(ca, cb)
        ca = na; cb = nb;
        p += 8;
    }
    if (p + 8 <= end) { PROC8(ca, cb) p += 8; }
    if (p + 4 <= end) {
        int4 c4 = *(const int4*)&colidx[p];
        PROC4(c4)
        p += 4;
    }
    for (; p < end; ++p) {
        int sn = colidx[p];
        float wq = __expf(lrelu(al_s[sn*4 + head] + ald_h));
        uint4 hv = ((const uint4*)(hbf + (size_t)sn * FEAT))[lane];
        ssum += wq;
        AGGR_STEP(hv, wq)
    }

    float inv = 1.f / (ssum + 1e-16f);
    const float* bp = bias + lane * 8;
    float oo[8] = {a0,a1,a2,a3,a4,a5,a6,a7};
    #pragma unroll
    for (int k = 0; k < 8; ++k) {
        float v = oo[k] * inv + bp[k];
        o[k] = v > 0.f ? v : __expf(v) - 1.f;
    }
}

// ======================= gemm epilogue (shared) =======================
__device__ __forceinline__ void gemm_epilogue(
    fx4* acc, const float* __restrict__ a_src, const float* __restrict__ a_dst,
    ushort* __restrict__ hbf_out, float* __restrict__ al_s_out,
    float* __restrict__ al_d_out, int n0, int node_l, int q)
{
    float ps[4] = {0.f, 0.f, 0.f, 0.f};
    float pd[4] = {0.f, 0.f, 0.f, 0.f};
    #pragma unroll
    for (int mt = 0; mt < 8; ++mt) {
        float4 as4 = *(const float4*)(a_src + mt * 16 + q * 4);
        float4 ad4 = *(const float4*)(a_dst + mt * 16 + q * 4);
        ps[mt >> 1] += acc[mt][0] * as4.x + acc[mt][1] * as4.y + acc[mt][2] * as4.z + acc[mt][3] * as4.w;
        pd[mt >> 1] += acc[mt][0] * ad4.x + acc[mt][1] * ad4.y + acc[mt][2] * ad4.z + acc[mt][3] * ad4.w;
        ushort4 hv;
        hv.x = f2bf(acc[mt][0]); hv.y = f2bf(acc[mt][1]);
        hv.z = f2bf(acc[mt][2]); hv.w = f2bf(acc[mt][3]);
        *(ushort4*)(hbf_out + (size_t)(n0 + node_l) * FEAT + mt * 16 + q * 4) = hv;
    }
    #pragma unroll
    for (int h = 0; h < 4; ++h) {
        ps[h] += __shfl_xor(ps[h], 16); ps[h] += __shfl_xor(ps[h], 32);
        pd[h] += __shfl_xor(pd[h], 16); pd[h] += __shfl_xor(pd[h], 32);
    }
    float vs = (q == 0) ? ps[0] : (q == 1) ? ps[1] : (q == 2) ? ps[2] : ps[3];
    float vd = (q == 0) ? pd[0] : (q == 1) ? pd[1] : (q == 2) ? pd[2] : pd[3];
    al_s_out[(n0 + node_l) * 4 + q] = vs;
    al_d_out[(n0 + node_l) * 4 + q] = vd;
}

// ======================= gemm0: fp32 input, A-frags from global bf16 W =======================
__device__ __forceinline__ void gemm0_body(
    const float* __restrict__ x, const ushort* __restrict__ wb,
    const float* __restrict__ a_src, const float* __restrict__ a_dst,
    ushort* __restrict__ hbf, float* __restrict__ al_s, float* __restrict__ al_d,
    int bid)
{
    const int t = threadIdx.x;
    const int lane = t & 63;
    const int node_l = lane & 15, q = lane >> 4;
    const int tile = bid * 4 + (t >> 6);
    if (tile >= GTILES) return;
    const int n0 = tile * 16;

    const float* rf = x + (size_t)(n0 + node_l) * FEAT + q * 8;
    short8 b0 = pack8f(rf);
    short8 b1 = pack8f(rf + 32);
    short8 b2 = pack8f(rf + 64);
    short8 b3 = pack8f(rf + 96);

    fx4 zero = {0.f, 0.f, 0.f, 0.f};
    fx4 acc[8];
    #pragma unroll
    for (int mt = 0; mt < 8; ++mt) acc[mt] = zero;
    #pragma unroll
    for (int kt = 0; kt < 4; ++kt) {
        short8 b = (kt == 0) ? b0 : (kt == 1) ? b1 : (kt == 2) ? b2 : b3;
        #pragma unroll
        for (int mt = 0; mt < 8; ++mt) {
            short8 a = *(const short8*)&wb[((mt * 4 + kt) * 64 + lane) * 8];
            acc[mt] = __builtin_amdgcn_mfma_f32_16x16x32_bf16(a, b, acc[mt], 0, 0, 0);
        }
    }
    gemm_epilogue(acc, a_src, a_dst, hbf, al_s, al_d, n0, node_l, q);
}

// ---- phase-A body: bucket-binned (dst,src) scatter into STRIDED pairs ----
// r17: no pre-hist/scan needed — per-block LDS hist reserves a run directly
// from the global bucket cursor; bucket base is fixed at b<<PSH.
__device__ __forceinline__ void phaseA_body(
    const int* __restrict__ ei, int E, int* bcursor, uint* __restrict__ pairs, int bid)
{
    __shared__ int lh[NBUCK], lb[NBUCK];
    int t = threadIdx.x;
    if (t < NBUCK) lh[t] = 0;
    __syncthreads();
    int base = bid * (256 * PA_EPT) + t;
    int s[PA_EPT], d[PA_EPT];
    #pragma unroll
    for (int k = 0; k < PA_EPT; ++k) {
        int i = base + k * 256;
        if (i < E)            { s[k] = ei[i]; d[k] = ei[E + i]; }
        else if (i < E + NN)  { s[k] = i - E; d[k] = s[k]; }
        else                  { s[k] = 0; d[k] = -1; }
        if (d[k] >= 0) atomicAdd(&lh[d[k] >> BSH], 1);
    }
    __syncthreads();
    if (t < NBUCK) {
        int c = lh[t];
        lb[t] = c ? (t << PSH) + atomicAdd(&bcursor[t], c) : 0;
        lh[t] = 0;
    }
    __syncthreads();
    #pragma unroll
    for (int k = 0; k < PA_EPT; ++k) {
        if (d[k] >= 0) {
            int b = d[k] >> BSH;
            int off = atomicAdd(&lh[b], 1);
            pairs[lb[b] + off] = ((uint)(d[k] & (BNODES - 1)) << 17) | (uint)s[k];
        }
    }
}

// ---- fused: gemm layer 0 || CSR phase A (data-independent) ----
__global__ __launch_bounds__(256, 2) void gemm0_phaseA_kernel(
    const float* __restrict__ x, const ushort* __restrict__ w0b,
    const float* __restrict__ a_src, const float* __restrict__ a_dst,
    ushort* __restrict__ hbf, float* __restrict__ al_s, float* __restrict__ al_d,
    const int* __restrict__ ei, int E, int* bcursor, uint* __restrict__ pairs)
{
    if (blockIdx.x < GEMMB)
        gemm0_body(x, w0b, a_src, a_dst, hbf, al_s, al_d, blockIdx.x);
    else
        phaseA_body(ei, E, bcursor, pairs, blockIdx.x - GEMMB);
}

// ======================= fused aggr(L) + gemm(L+1) =======================
__global__ __launch_bounds__(256, 4) void aggr_gemm_fused_kernel(
    const int* __restrict__ row_ptr, const int* __restrict__ colidx,
    const ushort* __restrict__ hbf_in, const float* __restrict__ al_s_in,
    const float* __restrict__ al_d_in, const float* __restrict__ bias,
    const ushort* __restrict__ wb, const float* __restrict__ a_src,
    const float* __restrict__ a_dst,
    ushort* __restrict__ hbf_out, float* __restrict__ al_s_out,
    float* __restrict__ al_d_out)
{
    __shared__ __align__(16) ushort HS[4][16 * HSTRIDE];   // 17 KiB, per-wave
    const int t = threadIdx.x;
    const int wv = t >> 6, lane = t & 63;
    const int tile = blockIdx.x * 4 + wv;
    if (tile >= GTILES) return;
    const int n0 = tile * 16;
    const int ng = lane >> 4, l16 = lane & 15;

    #pragma unroll 1
    for (int it = 0; it < 4; ++it) {
        int node = n0 + it * 4 + ng;
        float o[8];
        aggr_node(row_ptr, colidx, hbf_in, al_s_in, al_d_in, bias, node, l16, o);
        uint4 u;
        u.x = (uint)f2bf(o[0]) | ((uint)f2bf(o[1]) << 16);
        u.y = (uint)f2bf(o[2]) | ((uint)f2bf(o[3]) << 16);
        u.z = (uint)f2bf(o[4]) | ((uint)f2bf(o[5]) << 16);
        u.w = (uint)f2bf(o[6]) | ((uint)f2bf(o[7]) << 16);
        *(uint4*)&HS[wv][(it * 4 + ng) * HSTRIDE + l16 * 8] = u;
    }
    __builtin_amdgcn_sched_barrier(0);   // keep A-frag loads below the gather loop

    const int node_l = l16, q = ng;
    short8 b0 = *(const short8*)&HS[wv][node_l * HSTRIDE +      q * 8];
    short8 b1 = *(const short8*)&HS[wv][node_l * HSTRIDE + 32 + q * 8];
    short8 b2 = *(const short8*)&HS[wv][node_l * HSTRIDE + 64 + q * 8];
    short8 b3 = *(const short8*)&HS[wv][node_l * HSTRIDE + 96 + q * 8];

    fx4 zero = {0.f, 0.f, 0.f, 0.f};
    fx4 acc[8];
    #pragma unroll
    for (int mt = 0; mt < 8; ++mt) acc[mt] = zero;
    #pragma unroll
    for (int kt = 0; kt < 4; ++kt) {
        short8 b = (kt == 0) ? b0 : (kt == 1) ? b1 : (kt == 2) ? b2 : b3;
        #pragma unroll
        for (int mt = 0; mt < 8; ++mt) {
            short8 a = *(const short8*)&wb[((mt * 4 + kt) * 64 + lane) * 8];
            acc[mt] = __builtin_amdgcn_mfma_f32_16x16x32_bf16(a, b, acc[mt], 0, 0, 0);
        }
    }
    gemm_epilogue(acc, a_src, a_dst, hbf_out, al_s_out, al_d_out, n0, node_l, q);
}

// ======================= W prep + cursor init (one launch) =======================
__global__ __launch_bounds__(256) void wprep_init_kernel(
    const float* __restrict__ W0, const float* __restrict__ W1,
    const float* __restrict__ W2,
    ushort* __restrict__ wb0, ushort* __restrict__ wb1, ushort* __restrict__ wb2,
    int* __restrict__ bcursor)
{
    int t = threadIdx.x;
    if (blockIdx.x < WPREPB) {
        int b = blockIdx.x;                  // 0..WPREPB-1
        int mat = b >> 6;
        int idx = ((b & 63) << 8) | t;       // 0..16383
        const float* Wm = (mat == 0) ? W0 : (mat == 1) ? W1 : W2;
        ushort* wbm     = (mat == 0) ? wb0 : (mat == 1) ? wb1 : wb2;
        int k = idx >> 7, m = idx & 127;
        int mt = m >> 4, kt = k >> 5, qq = (k >> 3) & 3, j = k & 7;
        int ln = qq * 16 + (m & 15);
        wbm[((mt * 4 + kt) * 64 + ln) * 8 + j] = f2bf(Wm[idx]);
    } else {
        if (t < NBUCK) bcursor[t] = 0;
    }
}

// ======================= phase B: compact CSR from strided pairs =======================
// r17: computes the bucket prefix locally from bcursor counts (no scan kernel).
__global__ __launch_bounds__(256) void phaseB_kernel(
    const uint* __restrict__ pairs, const int* __restrict__ bcursor,
    int* __restrict__ row_ptr, int* __restrict__ colidx, int EP)
{
    __shared__ int nh[BNODES];
    __shared__ int ex[BNODES];
    __shared__ int ss[256];
    __shared__ int img[BCAP];
    int b = blockIdx.x, t = threadIdx.x;
    int node0 = b << BSH;
    int nend = min(NN - node0, BNODES);

    // local prefix over bucket counts -> compact base pb
    int vcnt = (t < NBUCK) ? bcursor[t] : 0;
    ss[t] = vcnt;
    __syncthreads();
    #pragma unroll
    for (int off = 1; off < 256; off <<= 1) {
        int x = (t >= off) ? ss[t - off] : 0;
        __syncthreads();
        ss[t] += x;
        __syncthreads();
    }
    int pb = (b > 0) ? ss[b - 1] : 0;
    int span = ss[b] - pb;
    const uint* src = pairs + ((size_t)b << PSH);
    __syncthreads();

    for (int j = t; j < BNODES; j += 256) nh[j] = 0;
    __syncthreads();
    for (int i = t; i < span; i += 256)
        atomicAdd(&nh[src[i] >> 17], 1);
    __syncthreads();
    int v0 = nh[2 * t], v1 = nh[2 * t + 1];
    int psc = v0 + v1;
    ss[t] = psc;
    __syncthreads();
    #pragma unroll
    for (int off = 1; off < 256; off <<= 1) {
        int x = (t >= off) ? ss[t - off] : 0;
        __syncthreads();
        ss[t] += x;
        __syncthreads();
    }
    int ep = ss[t] - psc;
    ex[2 * t] = ep;
    ex[2 * t + 1] = ep + v0;
    __syncthreads();
    for (int j = t; j < nend; j += 256) row_ptr[node0 + j] = pb + ex[j];
    if (b == NBUCK - 1 && t == 0) row_ptr[NN] = EP;
    for (int j = t; j < BNODES; j += 256) nh[j] = ex[j];   // reuse as cursors
    __syncthreads();
    if (span <= BCAP) {
        for (int i = t; i < span; i += 256) {
            uint p = src[i];
            int pos = atomicAdd(&nh[p >> 17], 1);
            img[pos] = (int)(p & SRCMASK);
        }
        __syncthreads();
        for (int i = t; i < span; i += 256) colidx[pb + i] = img[i];
    } else {
        for (int i = t; i < span; i += 256) {
            uint p = src[i];
            int pos = atomicAdd(&nh[p >> 17], 1);
            colidx[pb + pos] = (int)(p & SRCMASK);
        }
    }
}

// ======================= final aggr + FC(128->10) + log_softmax =======================
__global__ __launch_bounds__(256) void aggr_fc_kernel(
    const int* __restrict__ row_ptr, const int* __restrict__ colidx,
    const ushort* __restrict__ hbf, const float* __restrict__ al_s,
    const float* __restrict__ al_d, const float* __restrict__ bias,
    const float* __restrict__ fcW, const float* __restrict__ fcb,
    float* __restrict__ logout)
{
    __shared__ float WT[10][FEAT];
    __shared__ float bl[10];
    int t = threadIdx.x;
    for (int i = t; i < FEAT * 10; i += 256) {
        int k = i / 10, c = i % 10;
        WT[c][k] = fcW[i];
    }
    if (t < 10) bl[t] = fcb[t];
    __syncthreads();

    int node = blockIdx.x * 16 + (t >> 4);
    int lane = t & 15;
    float o[8];
    aggr_node(row_ptr, colidx, hbf, al_s, al_d, bias, node, lane, o);

    float lg[10];
    #pragma unroll
    for (int c = 0; c < 10; ++c) {
        const float* wr = &WT[c][lane * 8];
        float4 wa = *(const float4*)(wr);
        float4 wb = *(const float4*)(wr + 4);
        float acc = fmaf(o[0], wa.x, fmaf(o[1], wa.y, fmaf(o[2], wa.z, o[3] * wa.w)));
        acc = fmaf(o[4], wb.x, fmaf(o[5], wb.y, fmaf(o[6], wb.z, fmaf(o[7], wb.w, acc))));
        lg[c] = acc;
    }
    #pragma unroll
    for (int c = 0; c < 10; ++c) {
        lg[c] += __shfl_xor(lg[c], 1, 16);
        lg[c] += __shfl_xor(lg[c], 2, 16);
        lg[c] += __shfl_xor(lg[c], 4, 16);
        lg[c] += __shfl_xor(lg[c], 8, 16);
    }
    if (lane == 0) {
        float mx = -1e30f;
        #pragma unroll
        for (int c = 0; c < 10; ++c) { lg[c] += bl[c]; mx = fmaxf(mx, lg[c]); }
        float se = 0.f;
        #pragma unroll
        for (int c = 0; c < 10; ++c) se += __expf(lg[c] - mx);
        float lse = mx + __logf(se);
        float2* op = (float2*)(logout + (size_t)node * 10);
        #pragma unroll
        for (int c = 0; c < 5; ++c)
            op[c] = make_float2(lg[2*c] - lse, lg[2*c + 1] - lse);
    }
}

extern "C" void kernel_launch(void* const* d_in, const int* in_sizes, int n_in,
                              void* d_out, int out_size, void* d_ws, size_t ws_size,
                              hipStream_t stream)
{
    const float* x   = (const float*)d_in[0];
    const int*   ei  = (const int*)d_in[1];
    const float* W[3]   = {(const float*)d_in[2], (const float*)d_in[6],  (const float*)d_in[10]};
    const float* asr[3] = {(const float*)d_in[3], (const float*)d_in[7],  (const float*)d_in[11]};
    const float* ads[3] = {(const float*)d_in[4], (const float*)d_in[8],  (const float*)d_in[12]};
    const float* bs[3]  = {(const float*)d_in[5], (const float*)d_in[9],  (const float*)d_in[13]};
    const float* fcW = (const float*)d_in[14];
    const float* fcb = (const float*)d_in[15];
    const int E  = in_sizes[1] / 2;
    const int EP = E + NN;

    // workspace layout
    ushort* hbfA = (ushort*)d_ws;                       // [NN*FEAT] bf16
    ushort* hbfB = hbfA + (size_t)NN * FEAT;            // [NN*FEAT] bf16
    float* alsA  = (float*)(hbfB + (size_t)NN * FEAT);  // [NN*4]
    float* aldA  = alsA + (size_t)NN * NHEAD;           // [NN*4]
    float* alsB  = aldA + (size_t)NN * NHEAD;           // [NN*4]
    float* aldB  = alsB + (size_t)NN * NHEAD;           // [NN*4]
    int* row_ptr = (int*)(aldB + (size_t)NN * NHEAD);   // [NN+1]
    int* bcursor = row_ptr + NN + 1;                    // [NBUCK]
    uintptr_t pw = ((uintptr_t)(bcursor + NBUCK) + 15) & ~(uintptr_t)15;
    ushort* wb0  = (ushort*)pw;                         // [128*128] bf16, frag-ordered
    ushort* wb1  = wb0 + FEAT * FEAT;
    ushort* wb2  = wb1 + FEAT * FEAT;
    uint* pairs  = (uint*)(wb2 + FEAT * FEAT);          // [NBUCK<<PSH] strided
    int* colidx  = (int*)(pairs + ((size_t)NBUCK << PSH)); // [EP]

    const int pab = (EP + 256 * PA_EPT - 1) / (256 * PA_EPT);

    // 1. W prep + bucket cursor init
    wprep_init_kernel<<<WPREPB + 1, 256, 0, stream>>>(
        W[0], W[1], W[2], wb0, wb1, wb2, bcursor);

    // 2. layer-0 gemm || phase A (strided scatter, no pre-hist)
    gemm0_phaseA_kernel<<<GEMMB + pab, 256, 0, stream>>>(
        x, wb0, asr[0], ads[0], hbfA, alsA, aldA, ei, E, bcursor, pairs);

    // 3. compact CSR (local bucket prefix, no scan kernel)
    phaseB_kernel<<<NBUCK, 256, 0, stream>>>(pairs, bcursor, row_ptr, colidx, EP);

    // 4-5. fused aggr(L0)+gemm(L1), aggr(L1)+gemm(L2)
    aggr_gemm_fused_kernel<<<GEMMB, 256, 0, stream>>>(
        row_ptr, colidx, hbfA, alsA, aldA, bs[0], wb1, asr[1], ads[1],
        hbfB, alsB, aldB);
    aggr_gemm_fused_kernel<<<GEMMB, 256, 0, stream>>>(
        row_ptr, colidx, hbfB, alsB, aldB, bs[1], wb2, asr[2], ads[2],
        hbfA, alsA, aldA);

    // 6. final aggr + FC + log_softmax
    aggr_fc_kernel<<<(NN + 15) / 16, 256, 0, stream>>>(
        row_ptr, colidx, hbfA, alsA, aldA, bs[2], fcW, fcb, (float*)d_out);
}